// Round 6
// baseline (299.532 us; speedup 1.0000x reference)
//
#include <hip/hip_runtime.h>

#define PS 7
#define NP 10
#define WIN 20
#define STR 4
#define LL 14          // WIN - PS + 1
#define HALF 7
#define HH 160
#define WW 160
#define BCN 32         // B*C
#define NX 36          // positions per axis
#define PPOS 1296      // NX*NX
#define EMBD 128
#define NTASK (BCN * PPOS * NP)   // 414720
#define NEV (PPOS * NP)           // 12960 events per plane
#define CAP 512                   // per-tile event list capacity (8x8 tiles)
#define NTILE 400                 // 20x20 tiles of 8x8 per plane

// ---------------- phase 0: M2 = (Wp@Wb)^T, K[n] = (bp+pos_emb[n])@Wb + bb ----
// M2[d*49+j] = sum_e Wp[j][e]*Wb[e][d]  (transposed so k_den reads ROW d as
// wave-uniform s_loads from a 9.6KB K$-resident table).
// Also builds the 16x16 u64 lane-mask table MT (see k_apply).
__global__ __launch_bounds__(256) void k_mk(const float* __restrict__ Wp,
                                            const float* __restrict__ bp,
                                            const float* __restrict__ pe,
                                            const float* __restrict__ Wb,
                                            const float* __restrict__ bb,
                                            float* __restrict__ M2,
                                            float* __restrict__ K,
                                            unsigned long long* __restrict__ MT) {
    int t = blockIdx.x * 256 + threadIdx.x;
    if (t < 49 * 49) {
        int d = t / 49, j = t % 49;
        float acc = 0.f;
        for (int e = 0; e < EMBD; ++e) acc += Wp[j * EMBD + e] * Wb[e * 49 + d];
        M2[t] = acc;                       // M2[d][j]
    } else if (t < 49 * 49 + NP * 49) {
        int u = t - 49 * 49;
        int n = u / 49, d = u % 49;
        float acc = bb[d];
        for (int e = 0; e < EMBD; ++e) acc += (bp[e] + pe[n * EMBD + e]) * Wb[e * 49 + d];
        K[u] = acc;
    } else if (t < 49 * 49 + NP * 49 + 256) {
        int u = t - (49 * 49 + NP * 49);
        int ey = (u >> 4) - 7, ex = (u & 15) - 7;
        int r0 = ey > 0 ? ey : 0, r1 = ey + 6 < 7 ? ey + 6 : 7;
        int c0 = ex > 0 ? ex : 0, c1 = ex + 6 < 7 ? ex + 6 : 7;
        unsigned long long m = 0ull;
        if (r0 <= r1 && c0 <= c1) {
            unsigned colp = ((1u << (c1 - c0 + 1)) - 1u) << c0;
            for (int rr = r0; rr <= r1; ++rr)
                m |= (unsigned long long)colp << (8 * rr);
        }
        MT[u] = m;
    }
}

// DPP wave64 max-reduce: pure VALU (NO lgkmcnt), result valid in lane 63.
__device__ __forceinline__ float dpp_wave_max(float x) {
    int xi = __float_as_int(x);
#define DPP_STEP(ctrl)                                                          \
    {                                                                           \
        int t_ = __builtin_amdgcn_update_dpp(xi, xi, ctrl, 0xf, 0xf, false);    \
        xi = __float_as_int(fmaxf(__int_as_float(xi), __int_as_float(t_)));     \
    }
    DPP_STEP(0x111)  // row_shr:1
    DPP_STEP(0x112)  // row_shr:2
    DPP_STEP(0x114)  // row_shr:4
    DPP_STEP(0x118)  // row_shr:8
    DPP_STEP(0x142)  // row_bcast:15
    DPP_STEP(0x143)  // row_bcast:31
#undef DPP_STEP
    return __int_as_float(xi);
}

// DPP wave64 INCLUSIVE add-scan: pure VALU (no ds_permute / lgkmcnt).
__device__ __forceinline__ int dpp_scan_add(int x) {
    int t;
    t = __builtin_amdgcn_update_dpp(0, x, 0x111, 0xf, 0xf, true);  x += t;
    t = __builtin_amdgcn_update_dpp(0, x, 0x112, 0xf, 0xf, true);  x += t;
    t = __builtin_amdgcn_update_dpp(0, x, 0x114, 0xf, 0xf, true);  x += t;
    t = __builtin_amdgcn_update_dpp(0, x, 0x118, 0xf, 0xf, true);  x += t;
    t = __builtin_amdgcn_update_dpp(0, x, 0x142, 0xa, 0xf, false); x += t;
    t = __builtin_amdgcn_update_dpp(0, x, 0x143, 0xc, 0xf, false); x += t;
    return x;
}

// ---------------- phase 1: sim + top-10 -> xy only ---------------------------
// CRITICAL (round-18 lesson): wv via readfirstlane so pos/x/y/plane stay SGPR.
__global__ __launch_bounds__(256) void k_sim(const float* __restrict__ img,
                                             unsigned* __restrict__ xy) {
    int tid  = threadIdx.x;
    int wv   = __builtin_amdgcn_readfirstlane(tid >> 6);   // SGPR wave id
    int lane = tid & 63;
    int gt   = blockIdx.x * 4 + wv;    // SALU
    int pos  = gt % PPOS;
    int bc   = gt / PPOS;
    int ix = pos / NX, iy = pos % NX;
    int x = ix * STR, y = iy * STR;
    int xb0 = max(x - HALF, 0), yb0 = max(y - HALF, 0);
    int jmax = x + 6 - xb0;   // valid j <= jmax
    int imax = y + 6 - yb0;   // <= 13 always
    const float* plane = img + bc * (HH * WW);   // SGPR base

    // ref patch 7x7, wave-uniform -> s_loads (once per wave, not per-iter)
    float rf[49];
#pragma unroll
    for (int a = 0; a < PS; ++a)
#pragma unroll
        for (int b = 0; b < PS; ++b)
            rf[a * 7 + b] = plane[(y + a) * WW + (x + b)];

    int B = lane;                      // quad block id, valid < 56
    bool bval = B < 56;
    int gr = B / 14, c = B % 14;       // row-group, col
    int r0 = gr * 4;
    float acc[4] = {0.f, 0.f, 0.f, 0.f};
    const float* wb = plane + yb0 * WW + xb0 + c;
#pragma unroll
    for (int a = 0; a < 10; ++a) {
        int ra = min(r0 + a, 19);      // clamp keeps loads in-window
        const float* rp = wb + ra * WW;
#pragma unroll
        for (int b = 0; b < 7; ++b) {
            float tap = rp[b];
#pragma unroll
            for (int k = 0; k < 4; ++k) {
                int ai = a - k;
                if (ai >= 0 && ai < 7) acc[k] += tap * rf[ai * 7 + b];
            }
        }
    }
    float v[4]; int vidx[4];
#pragma unroll
    for (int k = 0; k < 4; ++k) {
        int rr = r0 + k;
        bool ok = bval && (rr <= imax) && (c <= jmax);  // imax<=13 masks rows 14/15
        v[k] = ok ? acc[k] : -INFINITY;
        vidx[k] = rr * 14 + c;         // monotone in lane per slot
    }

    int tbase = (bc * PPOS + pos) * NP;

    for (int n = 0; n < NP; ++n) {
        float bv = fmaxf(fmaxf(v[0], v[1]), fmaxf(v[2], v[3]));
        bv = dpp_wave_max(bv);                                 // VALU-only
        float bvs = __int_as_float(__builtin_amdgcn_readlane(__float_as_int(bv), 63));
        unsigned long long ms[4];
        ms[0] = __ballot(v[0] == bvs);
        ms[1] = __ballot(v[1] == bvs);
        ms[2] = __ballot(v[2] == bvs);
        ms[3] = __ballot(v[3] == bvs);
        int best = 1 << 30, slotw = 0, lanew = 0;
#pragma unroll
        for (int s = 0; s < 4; ++s) {
            if (ms[s]) {
                int l  = __ffsll(ms[s]) - 1;                       // SGPR
                int id = __builtin_amdgcn_readlane(vidx[s], l);    // SGPR
                if (id < best) { best = id; slotw = s; lanew = l; }
            }
        }
#pragma unroll
        for (int s = 0; s < 4; ++s)
            if (s == slotw && lane == lanew) v[s] = -INFINITY;

        int oy = best / 14, ox = best % 14;  // SALU
        int x_i = oy + xb0;        // source bug kept: col start = row off + xb0
        int y_i = ox + yb0;        // row start = col off + yb0
        if (lane == 0) xy[tbase + n] = (unsigned)x_i | ((unsigned)y_i << 8);
    }
}

// ---------------- phase 2: den — lane-per-task batched 49x49 matvec ----------
__global__ __launch_bounds__(256) void k_den(const float* __restrict__ img,
                                             const unsigned* __restrict__ xy,
                                             const float* __restrict__ M2,
                                             const float* __restrict__ Kg,
                                             float* __restrict__ pd) {
    __shared__ float xb[4][64 * 49];   // 4 waves x 12.25KB = 49KB
    int tid  = threadIdx.x;
    int wv   = tid >> 6;
    int lane = tid & 63;
    int t = blockIdx.x * 256 + tid;    // task id; grid exact (1620*256 == NTASK)
    int n = t % NP;
    int q = t / NP;
    int pos = q % PPOS;
    int bc  = q / PPOS;
    int ix = pos / NX, iy = pos % NX;
    int x = ix * STR, y = iy * STR;
    int xb0 = max(x - HALF, 0), yb0 = max(y - HALF, 0);
    unsigned u = xy[t];
    int x_i = (int)(u & 255u), y_i = (int)((u >> 8) & 255u);
    const float* src = img + bc * (HH * WW) + (yb0 + x_i - xb0) * WW + (xb0 + y_i - yb0);

    float tap[49];                     // transposed patch, per-lane vector loads
#pragma unroll
    for (int j = 0; j < 49; ++j) tap[j] = src[(j % 7) * WW + (j / 7)];

    const float* kp = Kg + n * 49;     // per-lane base (10 distinct rows, L1-hot)
    float* xbuf = xb[wv];
    for (int d = 0; d < 49; ++d) {
        const float* mrow = M2 + d * 49;    // wave-uniform -> s_loads, K$-hot
        float a0 = 0.f, a1 = 0.f;           // 2 chains for ILP
#pragma unroll
        for (int j = 0; j < 48; j += 2) {
            a0 = fmaf(tap[j],     mrow[j],     a0);
            a1 = fmaf(tap[j + 1], mrow[j + 1], a1);
        }
        a0 = fmaf(tap[48], mrow[48], a0);
        xbuf[lane * 49 + d] = (a0 + a1) + kp[d];
    }
    // coalesced flush: region pd[(first task of wave)*49 ...) is contiguous
    size_t base = (size_t)(blockIdx.x * 256 + wv * 64) * 49;
#pragma unroll
    for (int i = 0; i < 49; ++i)
        pd[base + i * 64 + lane] = xbuf[i * 64 + lane];
}

// ---------------- phase 3: build (LDS uint2 list) + replay -------------------
// Round-6: replay is software-pipelined. Round-5 showed k_apply latency-bound
// (FETCH 148->49MB + VALU ops cut, dur flat; VALUBusy 70->54%): per batch the
// wave serially waited lgkmcnt (entries) -> lgkmcnt (masks) -> vmcnt (pd dv,
// ~200cy L2). Now batches are double-buffered with STATIC A/B register roles
// (no runtime-indexed arrays -> no scratch): batch i+1's LDS entry reads,
// mask s_loads and dv global loads issue BEFORE batch i is processed, so all
// load latency hides under ~100cy of processing. Per-entry math byte-identical.
__global__ __launch_bounds__(128) void k_apply(const float* __restrict__ img,
                                               const unsigned* __restrict__ xy,
                                               const float* __restrict__ pd,
                                               const unsigned long long* __restrict__ mt,
                                               float* __restrict__ out) {
    __shared__ __align__(16) uint2 lsts[2][CAP];
    int tid  = threadIdx.x;
    int wv   = tid >> 6;
    int lane = tid & 63;
    int bs   = (blockIdx.x & 7) * 800 + (blockIdx.x >> 3);  // XCD-bijective
    int gt   = bs * 2 + wv;                  // global tile id
    int bc   = gt / NTILE;
    int tile = gt % NTILE;
    int tx0 = (tile % 20) * 8, ty0 = (tile / 20) * 8;
    int tx1 = tx0 + 7, ty1 = ty0 + 7;
    const unsigned* xs = xy + bc * NEV;
    uint2* lst = lsts[wv];

    // ---- build: interval-restricted scan ----
    int a0 = (tx0 <= 19) ? 0 : ((tx0 - 9) >> 2), a1 = min(35, (tx0 + 14) >> 2);
    int b0 = (ty0 <= 19) ? 0 : ((ty0 - 9) >> 2), b1 = min(35, (ty0 + 14) >> 2);
    if (a0 > b0) { int t0 = a0; a0 = b0; b0 = t0; int t1 = a1; a1 = b1; b1 = t1; }
    int lo0 = a0, lo1 = 0, len0, len1;
    if (b0 <= a1 + 1) { len0 = max(a1, b1) - lo0 + 1; len1 = 0; }
    else              { len0 = a1 - a0 + 1; lo1 = b0; len1 = b1 - b0 + 1; }
    int nU = len0 + len1;                    // <= 14
    unsigned m = 65536u / (unsigned)nU + 1u; // exact fastdiv (k < 4681, nU <= 14)
    int npos = nU * nU;

    unsigned cnt = 0;
    for (int base = 0; base < npos; base += 64) {
        int k = base + lane;
        bool valid = k < npos;
        unsigned kk = valid ? (unsigned)k : 0u;
        int ki = (int)((kk * m) >> 16);
        int kj = (int)kk - ki * nU;
        int ixp = (ki < len0) ? (lo0 + ki) : (lo1 + ki - len0);
        int iyp = (kj < len0) ? (lo0 + kj) : (lo1 + kj - len0);
        int pos = ixp * NX + iyp;
        const unsigned* ep = xs + pos * NP;

        unsigned ev[NP];
#pragma unroll
        for (int n = 0; n < NP; ++n) ev[n] = ep[n];

        unsigned rel = 0;
        unsigned w0[NP], w1[NP];
#pragma unroll
        for (int n = 0; n < NP; ++n) {
            unsigned u = ev[n];
            int x_i = (int)(u & 255u);
            int y_i = (int)((u >> 8) & 255u);
            bool ih = (x_i <= tx1) && (x_i + 6 >= tx0) &&
                      (y_i <= ty1) && (y_i + 6 >= ty0);
            bool ch = (x_i <= ty1) && (x_i + 6 >= ty0) &&
                      (y_i <= tx1) && (y_i + 6 >= tx0);
            bool any = valid && (ih || ch);
            rel |= any ? (1u << n) : 0u;
            int eyH = y_i - ty0, exH = x_i - tx0;
            int eyC = x_i - ty0, exC = y_i - tx0;
            unsigned hidx = ih ? (unsigned)(((eyH + 7) << 4) | (exH + 7)) : 0u;
            unsigned cidx = ch ? (unsigned)(((eyC + 7) << 4) | (exC + 7)) : 0u;
            unsigned s8q  = ih ? (unsigned)(((7 * eyH + exH) + 48) << 2) : 0u; // <=416, 9b
            w0[n] = (unsigned)(pos * NP + n);
            w1[n] = hidx | (cidx << 8) | (s8q << 16);
        }
        int myc  = __popc(rel);
        int scan = dpp_scan_add(myc);                        // VALU-only scan
        int total = __builtin_amdgcn_readlane(scan, 63);     // SGPR
        int excl  = (int)cnt + scan - myc;
        int w = excl;
#pragma unroll
        for (int n = 0; n < NP; ++n) {
            if ((rel >> n) & 1u) { if (w < CAP) lst[w] = make_uint2(w0[n], w1[n]); ++w; }
        }
        cnt += (unsigned)total;
    }
    if (cnt > CAP) cnt = CAP;
    unsigned cntp = (cnt + 15u) & ~15u;      // pad to 16 (2 batches/iter)
    if (cntp > CAP) cntp = CAP;
    if (lane < (int)(cntp - cnt)) lst[cnt + lane] = make_uint2(0u, 0u); // pad: zero masks
    int cntN = (int)cntp;

    // ---- apply: double-buffered batches of 8, static A/B roles ----
    int r8 = lane >> 3, c8 = lane & 7;
    int r  = ty0 + r8;
    int cc = tx0 + c8;
    float im = img[bc * (HH * WW) + r * WW + cc];
    float c  = 1.0f;
    const float* ds = pd + (size_t)bc * ((size_t)NEV * 49);
    int vOff2 = (r8 * 7 + c8) * 4 + 192;   // per-lane byte offset + s8q bias

    unsigned u0[8], u1[8];                 // transient decode (SGPR)

#define FETCH(IDX, HM, CM, DV)                                                 \
    {                                                                          \
        _Pragma("unroll")                                                      \
        for (int j = 0; j < 4; ++j) {      /* 4x ds_read_b128 broadcast */     \
            uint4 e2 = *reinterpret_cast<const uint4*>(&lst[(IDX) + 2 * j]);   \
            u0[2 * j]     = (unsigned)__builtin_amdgcn_readfirstlane((int)e2.x); \
            u1[2 * j]     = (unsigned)__builtin_amdgcn_readfirstlane((int)e2.y); \
            u0[2 * j + 1] = (unsigned)__builtin_amdgcn_readfirstlane((int)e2.z); \
            u1[2 * j + 1] = (unsigned)__builtin_amdgcn_readfirstlane((int)e2.w); \
        }                                                                      \
        _Pragma("unroll")                                                      \
        for (int j = 0; j < 8; ++j) {      /* 16x s_load_dwordx2, K$-hot */    \
            HM[j] = mt[u1[j] & 255u];                                          \
            CM[j] = mt[(u1[j] >> 8) & 255u];                                   \
        }                                                                      \
        _Pragma("unroll")                                                      \
        for (int j = 0; j < 8; ++j) {      /* 8x global_load v,off,s[base] */  \
            int t_ = (int)(u0[j] & 16383u);                                    \
            const char* dsb_ = (const char*)(ds + (size_t)t_ * 49);            \
            int boc_ = min(max(vOff2 - (int)((u1[j] >> 16) & 511u), 0), 192);  \
            DV[j] = *(const float*)(dsb_ + boc_);                              \
        }                                                                      \
    }

#define PROCESS(HM, CM, DV)                                                    \
    {                                                                          \
        _Pragma("unroll")                                                      \
        for (int j = 0; j < 8; ++j) {                                          \
            if (HM[j] != 0ull) {           /* uniform s_cbranch: image hit */  \
                float nim = fmaf(im, c, DV[j]) * __builtin_amdgcn_rcpf(c + 1.0f); \
                asm("v_cndmask_b32 %0, %0, %1, %2" : "+v"(im) : "v"(nim), "s"(HM[j])); \
            }                                                                  \
            if (CM[j] != 0ull) {           /* uniform s_cbranch: counter hit */\
                float inc;                                                     \
                asm("v_cndmask_b32 %0, 0, 1.0, %1" : "=v"(inc) : "s"(CM[j])); \
                c += inc;                  /* transposed-slice bug kept */     \
            }                                                                  \
        }                                                                      \
    }

    if (cntN > 0) {
        unsigned long long hmA[8], cmA[8], hmB[8], cmB[8];
        float dvA[8], dvB[8];
        FETCH(0, hmA, cmA, dvA);
        for (int i = 0; i < cntN; i += 16) {
            FETCH(i + 8, hmB, cmB, dvB);            // i+8 <= cntN-8: valid
            PROCESS(hmA, cmA, dvA);
            int ia = (i + 16 < cntN) ? (i + 16) : 0; // clamp: last prefetch reads
            FETCH(ia, hmA, cmA, dvA);                // batch 0 (discarded)
            PROCESS(hmB, cmB, dvB);
        }
    }
#undef FETCH
#undef PROCESS

    out[bc * (HH * WW) + r * WW + cc] = im;
}

extern "C" void kernel_launch(void* const* d_in, const int* in_sizes, int n_in,
                              void* d_out, int out_size, void* d_ws, size_t ws_size,
                              hipStream_t stream) {
    const float* img = (const float*)d_in[0];
    const float* Wp  = (const float*)d_in[1];
    const float* bp  = (const float*)d_in[2];
    const float* pe  = (const float*)d_in[3];
    const float* Wb  = (const float*)d_in[4];
    const float* bb  = (const float*)d_in[5];
    float* out = (float*)d_out;

    float* wsf = (float*)d_ws;
    float*              M2 = wsf;                               // 2401 floats (pad 2404)
    float*              K  = wsf + 2404;                        // 490 floats (pad 492)
    unsigned long long* MT = (unsigned long long*)(wsf + 2896); // 256 u64 = 512 floats
    unsigned*           xy = (unsigned*)(wsf + 3408);           // 414720 u32
    float*              pd = wsf + 3408 + NTASK;                // 20,321,280 floats

    k_mk<<<13, 256, 0, stream>>>(Wp, bp, pe, Wb, bb, M2, K, MT);
    k_sim<<<BCN * PPOS / 4, 256, 0, stream>>>(img, xy);
    k_den<<<NTASK / 256, 256, 0, stream>>>(img, xy, M2, K, pd);
    k_apply<<<BCN * NTILE / 2, 128, 0, stream>>>(img, xy, pd, MT, out);
}

// Round 7
// 289.390 us; speedup vs baseline: 1.0350x; 1.0350x over previous
//
#include <hip/hip_runtime.h>

#define PS 7
#define NP 10
#define WIN 20
#define STR 4
#define LL 14          // WIN - PS + 1
#define HALF 7
#define HH 160
#define WW 160
#define BCN 32         // B*C
#define NX 36          // positions per axis
#define PPOS 1296      // NX*NX
#define EMBD 128
#define NTASK (BCN * PPOS * NP)   // 414720
#define NEV (PPOS * NP)           // 12960 events per plane
#define CAP 512                   // per-tile event list capacity (8x8 tiles)
#define NTILE 400                 // 20x20 tiles of 8x8 per plane

// ---------------- phase 0: M2 = (Wp@Wb)^T, K[n] = (bp+pos_emb[n])@Wb + bb ----
// M2[d*49+j] = sum_e Wp[j][e]*Wb[e][d]  (transposed so k_den reads ROW d as
// wave-uniform s_loads from a 9.6KB K$-resident table).
// Also builds the 16x16 u64 lane-mask table MT (see k_apply).
__global__ __launch_bounds__(256) void k_mk(const float* __restrict__ Wp,
                                            const float* __restrict__ bp,
                                            const float* __restrict__ pe,
                                            const float* __restrict__ Wb,
                                            const float* __restrict__ bb,
                                            float* __restrict__ M2,
                                            float* __restrict__ K,
                                            unsigned long long* __restrict__ MT) {
    int t = blockIdx.x * 256 + threadIdx.x;
    if (t < 49 * 49) {
        int d = t / 49, j = t % 49;
        float acc = 0.f;
        for (int e = 0; e < EMBD; ++e) acc += Wp[j * EMBD + e] * Wb[e * 49 + d];
        M2[t] = acc;                       // M2[d][j]
    } else if (t < 49 * 49 + NP * 49) {
        int u = t - 49 * 49;
        int n = u / 49, d = u % 49;
        float acc = bb[d];
        for (int e = 0; e < EMBD; ++e) acc += (bp[e] + pe[n * EMBD + e]) * Wb[e * 49 + d];
        K[u] = acc;
    } else if (t < 49 * 49 + NP * 49 + 256) {
        int u = t - (49 * 49 + NP * 49);
        int ey = (u >> 4) - 7, ex = (u & 15) - 7;
        int r0 = ey > 0 ? ey : 0, r1 = ey + 6 < 7 ? ey + 6 : 7;
        int c0 = ex > 0 ? ex : 0, c1 = ex + 6 < 7 ? ex + 6 : 7;
        unsigned long long m = 0ull;
        if (r0 <= r1 && c0 <= c1) {
            unsigned colp = ((1u << (c1 - c0 + 1)) - 1u) << c0;
            for (int rr = r0; rr <= r1; ++rr)
                m |= (unsigned long long)colp << (8 * rr);
        }
        MT[u] = m;
    }
}

// DPP wave64 max-reduce: pure VALU (NO lgkmcnt), result valid in lane 63.
__device__ __forceinline__ float dpp_wave_max(float x) {
    int xi = __float_as_int(x);
#define DPP_STEP(ctrl)                                                          \
    {                                                                           \
        int t_ = __builtin_amdgcn_update_dpp(xi, xi, ctrl, 0xf, 0xf, false);    \
        xi = __float_as_int(fmaxf(__int_as_float(xi), __int_as_float(t_)));     \
    }
    DPP_STEP(0x111)  // row_shr:1
    DPP_STEP(0x112)  // row_shr:2
    DPP_STEP(0x114)  // row_shr:4
    DPP_STEP(0x118)  // row_shr:8
    DPP_STEP(0x142)  // row_bcast:15
    DPP_STEP(0x143)  // row_bcast:31
#undef DPP_STEP
    return __int_as_float(xi);
}

// DPP wave64 INCLUSIVE add-scan: pure VALU (no ds_permute / lgkmcnt).
__device__ __forceinline__ int dpp_scan_add(int x) {
    int t;
    t = __builtin_amdgcn_update_dpp(0, x, 0x111, 0xf, 0xf, true);  x += t;
    t = __builtin_amdgcn_update_dpp(0, x, 0x112, 0xf, 0xf, true);  x += t;
    t = __builtin_amdgcn_update_dpp(0, x, 0x114, 0xf, 0xf, true);  x += t;
    t = __builtin_amdgcn_update_dpp(0, x, 0x118, 0xf, 0xf, true);  x += t;
    t = __builtin_amdgcn_update_dpp(0, x, 0x142, 0xa, 0xf, false); x += t;
    t = __builtin_amdgcn_update_dpp(0, x, 0x143, 0xc, 0xf, false); x += t;
    return x;
}

// ---------------- phase 1: sim + top-10 -> xy only ---------------------------
// CRITICAL (round-18 lesson): wv via readfirstlane so pos/x/y/plane stay SGPR.
__global__ __launch_bounds__(256) void k_sim(const float* __restrict__ img,
                                             unsigned* __restrict__ xy) {
    int tid  = threadIdx.x;
    int wv   = __builtin_amdgcn_readfirstlane(tid >> 6);   // SGPR wave id
    int lane = tid & 63;
    int gt   = blockIdx.x * 4 + wv;    // SALU
    int pos  = gt % PPOS;
    int bc   = gt / PPOS;
    int ix = pos / NX, iy = pos % NX;
    int x = ix * STR, y = iy * STR;
    int xb0 = max(x - HALF, 0), yb0 = max(y - HALF, 0);
    int jmax = x + 6 - xb0;   // valid j <= jmax
    int imax = y + 6 - yb0;   // <= 13 always
    const float* plane = img + bc * (HH * WW);   // SGPR base

    // ref patch 7x7, wave-uniform -> s_loads (once per wave, not per-iter)
    float rf[49];
#pragma unroll
    for (int a = 0; a < PS; ++a)
#pragma unroll
        for (int b = 0; b < PS; ++b)
            rf[a * 7 + b] = plane[(y + a) * WW + (x + b)];

    int B = lane;                      // quad block id, valid < 56
    bool bval = B < 56;
    int gr = B / 14, c = B % 14;       // row-group, col
    int r0 = gr * 4;
    float acc[4] = {0.f, 0.f, 0.f, 0.f};
    const float* wb = plane + yb0 * WW + xb0 + c;
#pragma unroll
    for (int a = 0; a < 10; ++a) {
        int ra = min(r0 + a, 19);      // clamp keeps loads in-window
        const float* rp = wb + ra * WW;
#pragma unroll
        for (int b = 0; b < 7; ++b) {
            float tap = rp[b];
#pragma unroll
            for (int k = 0; k < 4; ++k) {
                int ai = a - k;
                if (ai >= 0 && ai < 7) acc[k] += tap * rf[ai * 7 + b];
            }
        }
    }
    float v[4]; int vidx[4];
#pragma unroll
    for (int k = 0; k < 4; ++k) {
        int rr = r0 + k;
        bool ok = bval && (rr <= imax) && (c <= jmax);  // imax<=13 masks rows 14/15
        v[k] = ok ? acc[k] : -INFINITY;
        vidx[k] = rr * 14 + c;         // monotone in lane per slot
    }

    int tbase = (bc * PPOS + pos) * NP;

    for (int n = 0; n < NP; ++n) {
        float bv = fmaxf(fmaxf(v[0], v[1]), fmaxf(v[2], v[3]));
        bv = dpp_wave_max(bv);                                 // VALU-only
        float bvs = __int_as_float(__builtin_amdgcn_readlane(__float_as_int(bv), 63));
        unsigned long long ms[4];
        ms[0] = __ballot(v[0] == bvs);
        ms[1] = __ballot(v[1] == bvs);
        ms[2] = __ballot(v[2] == bvs);
        ms[3] = __ballot(v[3] == bvs);
        int best = 1 << 30, slotw = 0, lanew = 0;
#pragma unroll
        for (int s = 0; s < 4; ++s) {
            if (ms[s]) {
                int l  = __ffsll(ms[s]) - 1;                       // SGPR
                int id = __builtin_amdgcn_readlane(vidx[s], l);    // SGPR
                if (id < best) { best = id; slotw = s; lanew = l; }
            }
        }
#pragma unroll
        for (int s = 0; s < 4; ++s)
            if (s == slotw && lane == lanew) v[s] = -INFINITY;

        int oy = best / 14, ox = best % 14;  // SALU
        int x_i = oy + xb0;        // source bug kept: col start = row off + xb0
        int y_i = ox + yb0;        // row start = col off + yb0
        if (lane == 0) xy[tbase + n] = (unsigned)x_i | ((unsigned)y_i << 8);
    }
}

// ---------------- phase 2: den — lane-per-task batched 49x49 matvec ----------
__global__ __launch_bounds__(256) void k_den(const float* __restrict__ img,
                                             const unsigned* __restrict__ xy,
                                             const float* __restrict__ M2,
                                             const float* __restrict__ Kg,
                                             float* __restrict__ pd) {
    __shared__ float xb[4][64 * 49];   // 4 waves x 12.25KB = 49KB
    int tid  = threadIdx.x;
    int wv   = tid >> 6;
    int lane = tid & 63;
    int t = blockIdx.x * 256 + tid;    // task id; grid exact (1620*256 == NTASK)
    int n = t % NP;
    int q = t / NP;
    int pos = q % PPOS;
    int bc  = q / PPOS;
    int ix = pos / NX, iy = pos % NX;
    int x = ix * STR, y = iy * STR;
    int xb0 = max(x - HALF, 0), yb0 = max(y - HALF, 0);
    unsigned u = xy[t];
    int x_i = (int)(u & 255u), y_i = (int)((u >> 8) & 255u);
    const float* src = img + bc * (HH * WW) + (yb0 + x_i - xb0) * WW + (xb0 + y_i - yb0);

    float tap[49];                     // transposed patch, per-lane vector loads
#pragma unroll
    for (int j = 0; j < 49; ++j) tap[j] = src[(j % 7) * WW + (j / 7)];

    const float* kp = Kg + n * 49;     // per-lane base (10 distinct rows, L1-hot)
    float* xbuf = xb[wv];
    for (int d = 0; d < 49; ++d) {
        const float* mrow = M2 + d * 49;    // wave-uniform -> s_loads, K$-hot
        float a0 = 0.f, a1 = 0.f;           // 2 chains for ILP
#pragma unroll
        for (int j = 0; j < 48; j += 2) {
            a0 = fmaf(tap[j],     mrow[j],     a0);
            a1 = fmaf(tap[j + 1], mrow[j + 1], a1);
        }
        a0 = fmaf(tap[48], mrow[48], a0);
        xbuf[lane * 49 + d] = (a0 + a1) + kp[d];
    }
    // coalesced flush: region pd[(first task of wave)*49 ...) is contiguous
    size_t base = (size_t)(blockIdx.x * 256 + wv * 64) * 49;
#pragma unroll
    for (int i = 0; i < 49; ++i)
        pd[base + i * 64 + lane] = xbuf[i * 64 + lane];
}

// ---------------- phase 3: build (LDS uint2 list) + replay -------------------
// Round-7 replay: single-buffer batches of 8 (round-6 A/B pipeline reverted:
// it was null-to-negative). Two latency fixes instead:
//  (a) NO uniform s_cbranch skips — round 5/6 showed ~360 taken scalar
//      branches/tile trade VALU for front-end bubbles at zero net gain;
//      straight-line masked ops instead.
//  (b) v_rcp hoisted OFF the im critical chain: the counter sequence cv[j]
//      (c after entries 0..j-1) depends only on cm masks, so inc/cv/rcp are
//      precomputed per batch; the im-fold is then fmaf->mul->cndmask (12cy)
//      instead of fmaf->rcp(1/4-rate)->mul->cndmask (~28cy). Bit-identical:
//      same float ops, same order, just computed early.
//  (c) boc clamp dropped: unclamped offset strays at most -4/+216B around a
//      valid pd row (still inside the workspace); those lanes' dv is masked
//      off by hm anyway.
__global__ __launch_bounds__(128) void k_apply(const float* __restrict__ img,
                                               const unsigned* __restrict__ xy,
                                               const float* __restrict__ pd,
                                               const unsigned long long* __restrict__ mt,
                                               float* __restrict__ out) {
    __shared__ __align__(16) uint2 lsts[2][CAP];
    int tid  = threadIdx.x;
    int wv   = tid >> 6;
    int lane = tid & 63;
    int bs   = (blockIdx.x & 7) * 800 + (blockIdx.x >> 3);  // XCD-bijective
    int gt   = bs * 2 + wv;                  // global tile id
    int bc   = gt / NTILE;
    int tile = gt % NTILE;
    int tx0 = (tile % 20) * 8, ty0 = (tile / 20) * 8;
    int tx1 = tx0 + 7, ty1 = ty0 + 7;
    const unsigned* xs = xy + bc * NEV;
    uint2* lst = lsts[wv];

    // ---- build: interval-restricted scan ----
    int a0 = (tx0 <= 19) ? 0 : ((tx0 - 9) >> 2), a1 = min(35, (tx0 + 14) >> 2);
    int b0 = (ty0 <= 19) ? 0 : ((ty0 - 9) >> 2), b1 = min(35, (ty0 + 14) >> 2);
    if (a0 > b0) { int t0 = a0; a0 = b0; b0 = t0; int t1 = a1; a1 = b1; b1 = t1; }
    int lo0 = a0, lo1 = 0, len0, len1;
    if (b0 <= a1 + 1) { len0 = max(a1, b1) - lo0 + 1; len1 = 0; }
    else              { len0 = a1 - a0 + 1; lo1 = b0; len1 = b1 - b0 + 1; }
    int nU = len0 + len1;                    // <= 14
    unsigned m = 65536u / (unsigned)nU + 1u; // exact fastdiv (k < 4681, nU <= 14)
    int npos = nU * nU;

    unsigned cnt = 0;
    for (int base = 0; base < npos; base += 64) {
        int k = base + lane;
        bool valid = k < npos;
        unsigned kk = valid ? (unsigned)k : 0u;
        int ki = (int)((kk * m) >> 16);
        int kj = (int)kk - ki * nU;
        int ixp = (ki < len0) ? (lo0 + ki) : (lo1 + ki - len0);
        int iyp = (kj < len0) ? (lo0 + kj) : (lo1 + kj - len0);
        int pos = ixp * NX + iyp;
        const unsigned* ep = xs + pos * NP;

        unsigned ev[NP];
#pragma unroll
        for (int n = 0; n < NP; ++n) ev[n] = ep[n];

        unsigned rel = 0;
        unsigned w0[NP], w1[NP];
#pragma unroll
        for (int n = 0; n < NP; ++n) {
            unsigned u = ev[n];
            int x_i = (int)(u & 255u);
            int y_i = (int)((u >> 8) & 255u);
            int exH = x_i - tx0, eyH = y_i - ty0;   // shared subs (CSE with pack)
            int eyC = x_i - ty0, exC = y_i - tx0;
            bool ih = ((unsigned)(exH + 6) <= 13u) & ((unsigned)(eyH + 6) <= 13u);
            bool ch = ((unsigned)(eyC + 6) <= 13u) & ((unsigned)(exC + 6) <= 13u);
            bool any = valid && (ih || ch);
            rel |= any ? (1u << n) : 0u;
            unsigned hidx = ih ? (unsigned)(((eyH + 7) << 4) | (exH + 7)) : 0u;
            unsigned cidx = ch ? (unsigned)(((eyC + 7) << 4) | (exC + 7)) : 0u;
            unsigned s8q  = ih ? (unsigned)(((7 * eyH + exH) + 48) << 2) : 0u; // <=416, 9b
            w0[n] = (unsigned)(pos * NP + n);
            w1[n] = hidx | (cidx << 8) | (s8q << 16);
        }
        int myc  = __popc(rel);
        int scan = dpp_scan_add(myc);                        // VALU-only scan
        int total = __builtin_amdgcn_readlane(scan, 63);     // SGPR
        int excl  = (int)cnt + scan - myc;
        int w = excl;
#pragma unroll
        for (int n = 0; n < NP; ++n) {
            if ((rel >> n) & 1u) { if (w < CAP) lst[w] = make_uint2(w0[n], w1[n]); ++w; }
        }
        cnt += (unsigned)total;
    }
    if (cnt > CAP) cnt = CAP;
    unsigned cntp = (cnt + 7u) & ~7u;
    if (cntp > CAP) cntp = CAP;
    if (lane < (int)(cntp - cnt)) lst[cnt + lane] = make_uint2(0u, 0u); // pad: zero masks
    int cntN = (int)cntp;

    // ---- apply: batch-of-8, straight-line masked ops, rcp off-chain ----
    int r8 = lane >> 3, c8 = lane & 7;
    int r  = ty0 + r8;
    int cc = tx0 + c8;
    float im = img[bc * (HH * WW) + r * WW + cc];
    float c  = 1.0f;
    const float* ds = pd + (size_t)bc * ((size_t)NEV * 49);
    int vOff2 = (r8 * 7 + c8) * 4 + 192;   // per-lane byte offset + s8q bias

    for (int i = 0; i < cntN; i += 8) {
        unsigned u0[8], u1[8];
        float    dv[8];
#pragma unroll
        for (int j = 0; j < 4; ++j) {      // 4x ds_read_b128 (2 entries each)
            uint4 e2 = *reinterpret_cast<const uint4*>(&lst[i + 2 * j]);
            u0[2 * j]     = (unsigned)__builtin_amdgcn_readfirstlane((int)e2.x);
            u1[2 * j]     = (unsigned)__builtin_amdgcn_readfirstlane((int)e2.y);
            u0[2 * j + 1] = (unsigned)__builtin_amdgcn_readfirstlane((int)e2.z);
            u1[2 * j + 1] = (unsigned)__builtin_amdgcn_readfirstlane((int)e2.w);
        }
        unsigned long long hm[8], cm[8];
#pragma unroll
        for (int j = 0; j < 8; ++j) {      // 16x s_load_dwordx2 from 2KB K$-hot table
            hm[j] = mt[u1[j] & 255u];
            cm[j] = mt[(u1[j] >> 8) & 255u];
        }
#pragma unroll
        for (int j = 0; j < 8; ++j) {      // 8x global_load v,off,s[base]
            int t_ = (int)(u0[j] & 16383u);
            const char* dsb = (const char*)(ds + (size_t)t_ * 49);
            int boc = vOff2 - (int)((u1[j] >> 16) & 511u);  // unclamped (see (c))
            dv[j] = *(const float*)(dsb + boc);
        }
        // counter chain + rcp: independent of im, precomputed (same float ops
        // in the same order as the serial version -> bit-identical)
        float inc[8], cv[8], rv[8];
#pragma unroll
        for (int j = 0; j < 8; ++j)
            asm("v_cndmask_b32 %0, 0, 1.0, %1" : "=v"(inc[j]) : "s"(cm[j]));
        cv[0] = c;
#pragma unroll
        for (int j = 1; j < 8; ++j) cv[j] = cv[j - 1] + inc[j - 1];
        c = cv[7] + inc[7];
#pragma unroll
        for (int j = 0; j < 8; ++j) rv[j] = __builtin_amdgcn_rcpf(cv[j] + 1.0f);
        // im fold: fmaf -> mul -> cndmask per entry (12cy links)
#pragma unroll
        for (int j = 0; j < 8; ++j) {
            float nim = fmaf(im, cv[j], dv[j]) * rv[j];
            asm("v_cndmask_b32 %0, %0, %1, %2" : "+v"(im) : "v"(nim), "s"(hm[j]));
        }
    }
    out[bc * (HH * WW) + r * WW + cc] = im;
}

extern "C" void kernel_launch(void* const* d_in, const int* in_sizes, int n_in,
                              void* d_out, int out_size, void* d_ws, size_t ws_size,
                              hipStream_t stream) {
    const float* img = (const float*)d_in[0];
    const float* Wp  = (const float*)d_in[1];
    const float* bp  = (const float*)d_in[2];
    const float* pe  = (const float*)d_in[3];
    const float* Wb  = (const float*)d_in[4];
    const float* bb  = (const float*)d_in[5];
    float* out = (float*)d_out;

    float* wsf = (float*)d_ws;
    float*              M2 = wsf;                               // 2401 floats (pad 2404)
    float*              K  = wsf + 2404;                        // 490 floats (pad 492)
    unsigned long long* MT = (unsigned long long*)(wsf + 2896); // 256 u64 = 512 floats
    unsigned*           xy = (unsigned*)(wsf + 3408);           // 414720 u32
    float*              pd = wsf + 3408 + NTASK;                // 20,321,280 floats

    k_mk<<<13, 256, 0, stream>>>(Wp, bp, pe, Wb, bb, M2, K, MT);
    k_sim<<<BCN * PPOS / 4, 256, 0, stream>>>(img, xy);
    k_den<<<NTASK / 256, 256, 0, stream>>>(img, xy, M2, K, pd);
    k_apply<<<BCN * NTILE / 2, 128, 0, stream>>>(img, xy, pd, MT, out);
}

// Round 8
// 287.384 us; speedup vs baseline: 1.0423x; 1.0070x over previous
//
#include <hip/hip_runtime.h>

#define PS 7
#define NP 10
#define WIN 20
#define STR 4
#define LL 14          // WIN - PS + 1
#define HALF 7
#define HH 160
#define WW 160
#define BCN 32         // B*C
#define NX 36          // positions per axis
#define PPOS 1296      // NX*NX
#define EMBD 128
#define NTASK (BCN * PPOS * NP)   // 414720
#define NEV (PPOS * NP)           // 12960 events per plane
#define CAP 512                   // per-tile event list capacity (8x8 tiles)
#define NTILE 400                 // 20x20 tiles of 8x8 per plane

// ---------------- phase 0: M = Wp@Wb ([j][d]), K[n] = (bp+pos_emb[n])@Wb + bb
// M[j*49+d]: k_sim reads column d coalesced (Mc[j] = M[j*49+ld]).
// Also builds the 16x16 u64 lane-mask table MT (see k_apply).
__global__ __launch_bounds__(256) void k_mk(const float* __restrict__ Wp,
                                            const float* __restrict__ bp,
                                            const float* __restrict__ pe,
                                            const float* __restrict__ Wb,
                                            const float* __restrict__ bb,
                                            float* __restrict__ M,
                                            float* __restrict__ K,
                                            unsigned long long* __restrict__ MT) {
    int t = blockIdx.x * 256 + threadIdx.x;
    if (t < 49 * 49) {
        int k = t / 49, d = t % 49;
        float acc = 0.f;
        for (int e = 0; e < EMBD; ++e) acc += Wp[k * EMBD + e] * Wb[e * 49 + d];
        M[t] = acc;                        // M[j][d]
    } else if (t < 49 * 49 + NP * 49) {
        int u = t - 49 * 49;
        int n = u / 49, d = u % 49;
        float acc = bb[d];
        for (int e = 0; e < EMBD; ++e) acc += (bp[e] + pe[n * EMBD + e]) * Wb[e * 49 + d];
        K[u] = acc;
    } else if (t < 49 * 49 + NP * 49 + 256) {
        int u = t - (49 * 49 + NP * 49);
        int ey = (u >> 4) - 7, ex = (u & 15) - 7;
        int r0 = ey > 0 ? ey : 0, r1 = ey + 6 < 7 ? ey + 6 : 7;
        int c0 = ex > 0 ? ex : 0, c1 = ex + 6 < 7 ? ex + 6 : 7;
        unsigned long long m = 0ull;
        if (r0 <= r1 && c0 <= c1) {
            unsigned colp = ((1u << (c1 - c0 + 1)) - 1u) << c0;
            for (int rr = r0; rr <= r1; ++rr)
                m |= (unsigned long long)colp << (8 * rr);
        }
        MT[u] = m;
    }
}

// DPP wave64 max-reduce: pure VALU (NO lgkmcnt), result valid in lane 63.
__device__ __forceinline__ float dpp_wave_max(float x) {
    int xi = __float_as_int(x);
#define DPP_STEP(ctrl)                                                          \
    {                                                                           \
        int t_ = __builtin_amdgcn_update_dpp(xi, xi, ctrl, 0xf, 0xf, false);    \
        xi = __float_as_int(fmaxf(__int_as_float(xi), __int_as_float(t_)));     \
    }
    DPP_STEP(0x111)  // row_shr:1
    DPP_STEP(0x112)  // row_shr:2
    DPP_STEP(0x114)  // row_shr:4
    DPP_STEP(0x118)  // row_shr:8
    DPP_STEP(0x142)  // row_bcast:15
    DPP_STEP(0x143)  // row_bcast:31
#undef DPP_STEP
    return __int_as_float(xi);
}

// DPP wave64 INCLUSIVE add-scan: pure VALU (no ds_permute / lgkmcnt).
__device__ __forceinline__ int dpp_scan_add(int x) {
    int t;
    t = __builtin_amdgcn_update_dpp(0, x, 0x111, 0xf, 0xf, true);  x += t;
    t = __builtin_amdgcn_update_dpp(0, x, 0x112, 0xf, 0xf, true);  x += t;
    t = __builtin_amdgcn_update_dpp(0, x, 0x114, 0xf, 0xf, true);  x += t;
    t = __builtin_amdgcn_update_dpp(0, x, 0x118, 0xf, 0xf, true);  x += t;
    t = __builtin_amdgcn_update_dpp(0, x, 0x142, 0xa, 0xf, false); x += t;
    t = __builtin_amdgcn_update_dpp(0, x, 0x143, 0xc, 0xf, false); x += t;
    return x;
}

// ---------------- phase 1: sim + top-10 + FUSED den (LDS-tap edition) --------
// Round-8: den re-fused (the round-4 split cost sim+den ~167us vs 126 fused;
// k_den's 64-lanes-x-distinct-windows tap loads were ~1.3GB of line-granular
// L2 traffic). The original fused kernel's stall — 490 wave-uniform tap
// s_loads thrashing the 16KB scalar K$ across ~13 resident waves — is fixed
// by staging the wave's 20x20 window in LDS once (1.6KB) and reading taps as
// BROADCAST ds_reads (one base VGPR + imm offsets; uniform addr = conflict-
// free; deep lgkm queue; no sK$ involvement). den math is byte-identical to
// the accepted round-3 body (Kg-seeded 4-chain, j+=4, pairwise combine).
// CRITICAL (round-18 lesson): wv via readfirstlane so pos/x/y/plane stay SGPR.
__global__ __launch_bounds__(256) void k_sim(const float* __restrict__ img,
                                             const float* __restrict__ Mg,
                                             const float* __restrict__ Kg,
                                             unsigned* __restrict__ xy,
                                             float* __restrict__ pd) {
    __shared__ float winb[4][400];     // 4 waves x 1.6KB
    int tid  = threadIdx.x;
    int wv   = __builtin_amdgcn_readfirstlane(tid >> 6);   // SGPR wave id
    int lane = tid & 63;
    int gt   = blockIdx.x * 4 + wv;    // SALU
    int pos  = gt % PPOS;
    int bc   = gt / PPOS;
    int ix = pos / NX, iy = pos % NX;
    int x = ix * STR, y = iy * STR;
    int xb0 = max(x - HALF, 0), yb0 = max(y - HALF, 0);
    int jmax = x + 6 - xb0;   // valid j <= jmax
    int imax = y + 6 - yb0;   // <= 13 always
    const float* plane = img + bc * (HH * WW);   // SGPR base
    float* winw = winb[wv];

    // stage the 20x20 window into LDS (coalesced; 7 loads/lane)
#pragma unroll
    for (int i0 = 0; i0 < 448; i0 += 64) {
        int i = i0 + lane;
        if (i < 400) winw[i] = plane[(yb0 + i / 20) * WW + (xb0 + i % 20)];
    }
    __syncthreads();

    // ref patch 7x7, wave-uniform -> s_loads (once per wave)
    float rf[49];
#pragma unroll
    for (int a = 0; a < PS; ++a)
#pragma unroll
        for (int b = 0; b < PS; ++b)
            rf[a * 7 + b] = plane[(y + a) * WW + (x + b)];

    int B = lane;                      // quad block id, valid < 56
    bool bval = B < 56;
    int gr = B / 14, c = B % 14;       // row-group, col
    int r0 = gr * 4;
    float acc[4] = {0.f, 0.f, 0.f, 0.f};
    const float* wb = plane + yb0 * WW + xb0 + c;
#pragma unroll
    for (int a = 0; a < 10; ++a) {
        int ra = min(r0 + a, 19);      // clamp keeps loads in-window
        const float* rp = wb + ra * WW;
#pragma unroll
        for (int b = 0; b < 7; ++b) {
            float tap = rp[b];
#pragma unroll
            for (int k = 0; k < 4; ++k) {
                int ai = a - k;
                if (ai >= 0 && ai < 7) acc[k] += tap * rf[ai * 7 + b];
            }
        }
    }
    float v[4]; int vidx[4];
#pragma unroll
    for (int k = 0; k < 4; ++k) {
        int rr = r0 + k;
        bool ok = bval && (rr <= imax) && (c <= jmax);  // imax<=13 masks rows 14/15
        v[k] = ok ? acc[k] : -INFINITY;
        vidx[k] = rr * 14 + c;         // monotone in lane per slot
    }

    // M column d cached per lane (rf[] live range ends above -> regs reused)
    int ld = min(lane, 48);
    float Mc[49];
#pragma unroll
    for (int j = 0; j < 49; ++j) Mc[j] = Mg[j * 49 + ld];  // coalesced, L1-hot

    bool act = lane < 49;
    int tbase = (bc * PPOS + pos) * NP;

    for (int n = 0; n < NP; ++n) {
        float bv = fmaxf(fmaxf(v[0], v[1]), fmaxf(v[2], v[3]));
        bv = dpp_wave_max(bv);                                 // VALU-only
        float bvs = __int_as_float(__builtin_amdgcn_readlane(__float_as_int(bv), 63));
        unsigned long long ms[4];
        ms[0] = __ballot(v[0] == bvs);
        ms[1] = __ballot(v[1] == bvs);
        ms[2] = __ballot(v[2] == bvs);
        ms[3] = __ballot(v[3] == bvs);
        int best = 1 << 30, slotw = 0, lanew = 0;
#pragma unroll
        for (int s = 0; s < 4; ++s) {
            if (ms[s]) {
                int l  = __ffsll(ms[s]) - 1;                       // SGPR
                int id = __builtin_amdgcn_readlane(vidx[s], l);    // SGPR
                if (id < best) { best = id; slotw = s; lanew = l; }
            }
        }
#pragma unroll
        for (int s = 0; s < 4; ++s)
            if (s == slotw && lane == lanew) v[s] = -INFINITY;

        int oy = best / 14, ox = best % 14;  // SALU, window-relative offsets
        int x_i = oy + xb0;        // source bug kept: col start = row off + xb0
        int y_i = ox + yb0;        // row start = col off + yb0
        int t = tbase + n;
        if (lane == 0) xy[t] = (unsigned)x_i | ((unsigned)y_i << 8);

        // taps from the LDS window: broadcast ds_reads, one base + imm offsets
        // tap[j] = win[oy + j%7][ox + j/7]  (transposed patch, as round-3)
        const float* tb = winw + oy * 20 + ox;
        float tap[49];
#pragma unroll
        for (int j = 0; j < 49; ++j)
            tap[j] = tb[(j % 7) * 20 + (j / 7)];

        // den[lane] = K[n][lane] + sum_j tap_j*Mc[j]; 4 chains (round-3 order)
        float d0 = Kg[n * 49 + ld], d1 = 0.f, d2 = 0.f, d3 = 0.f;
#pragma unroll
        for (int j = 0; j < 48; j += 4) {
            d0 = fmaf(tap[j + 0], Mc[j + 0], d0);
            d1 = fmaf(tap[j + 1], Mc[j + 1], d1);
            d2 = fmaf(tap[j + 2], Mc[j + 2], d2);
            d3 = fmaf(tap[j + 3], Mc[j + 3], d3);
        }
        d0 = fmaf(tap[48], Mc[48], d0);
        float den = (d0 + d1) + (d2 + d3);
        if (act) pd[(size_t)t * 49 + lane] = den;
    }
}

// ---------------- phase 3: build (LDS uint2 list) + replay -------------------
// Byte-identical to round 7 (isolation): straight-line masked ops, rcp
// off-chain, unclamped boc, XCD-bijective swizzle, DPP scan build.
__global__ __launch_bounds__(128) void k_apply(const float* __restrict__ img,
                                               const unsigned* __restrict__ xy,
                                               const float* __restrict__ pd,
                                               const unsigned long long* __restrict__ mt,
                                               float* __restrict__ out) {
    __shared__ __align__(16) uint2 lsts[2][CAP];
    int tid  = threadIdx.x;
    int wv   = tid >> 6;
    int lane = tid & 63;
    int bs   = (blockIdx.x & 7) * 800 + (blockIdx.x >> 3);  // XCD-bijective
    int gt   = bs * 2 + wv;                  // global tile id
    int bc   = gt / NTILE;
    int tile = gt % NTILE;
    int tx0 = (tile % 20) * 8, ty0 = (tile / 20) * 8;
    int tx1 = tx0 + 7, ty1 = ty0 + 7;
    const unsigned* xs = xy + bc * NEV;
    uint2* lst = lsts[wv];

    // ---- build: interval-restricted scan ----
    int a0 = (tx0 <= 19) ? 0 : ((tx0 - 9) >> 2), a1 = min(35, (tx0 + 14) >> 2);
    int b0 = (ty0 <= 19) ? 0 : ((ty0 - 9) >> 2), b1 = min(35, (ty0 + 14) >> 2);
    if (a0 > b0) { int t0 = a0; a0 = b0; b0 = t0; int t1 = a1; a1 = b1; b1 = t1; }
    int lo0 = a0, lo1 = 0, len0, len1;
    if (b0 <= a1 + 1) { len0 = max(a1, b1) - lo0 + 1; len1 = 0; }
    else              { len0 = a1 - a0 + 1; lo1 = b0; len1 = b1 - b0 + 1; }
    int nU = len0 + len1;                    // <= 14
    unsigned m = 65536u / (unsigned)nU + 1u; // exact fastdiv (k < 4681, nU <= 14)
    int npos = nU * nU;

    unsigned cnt = 0;
    for (int base = 0; base < npos; base += 64) {
        int k = base + lane;
        bool valid = k < npos;
        unsigned kk = valid ? (unsigned)k : 0u;
        int ki = (int)((kk * m) >> 16);
        int kj = (int)kk - ki * nU;
        int ixp = (ki < len0) ? (lo0 + ki) : (lo1 + ki - len0);
        int iyp = (kj < len0) ? (lo0 + kj) : (lo1 + kj - len0);
        int pos = ixp * NX + iyp;
        const unsigned* ep = xs + pos * NP;

        unsigned ev[NP];
#pragma unroll
        for (int n = 0; n < NP; ++n) ev[n] = ep[n];

        unsigned rel = 0;
        unsigned w0[NP], w1[NP];
#pragma unroll
        for (int n = 0; n < NP; ++n) {
            unsigned u = ev[n];
            int x_i = (int)(u & 255u);
            int y_i = (int)((u >> 8) & 255u);
            int exH = x_i - tx0, eyH = y_i - ty0;   // shared subs (CSE with pack)
            int eyC = x_i - ty0, exC = y_i - tx0;
            bool ih = ((unsigned)(exH + 6) <= 13u) & ((unsigned)(eyH + 6) <= 13u);
            bool ch = ((unsigned)(eyC + 6) <= 13u) & ((unsigned)(exC + 6) <= 13u);
            bool any = valid && (ih || ch);
            rel |= any ? (1u << n) : 0u;
            unsigned hidx = ih ? (unsigned)(((eyH + 7) << 4) | (exH + 7)) : 0u;
            unsigned cidx = ch ? (unsigned)(((eyC + 7) << 4) | (exC + 7)) : 0u;
            unsigned s8q  = ih ? (unsigned)(((7 * eyH + exH) + 48) << 2) : 0u; // <=416, 9b
            w0[n] = (unsigned)(pos * NP + n);
            w1[n] = hidx | (cidx << 8) | (s8q << 16);
        }
        int myc  = __popc(rel);
        int scan = dpp_scan_add(myc);                        // VALU-only scan
        int total = __builtin_amdgcn_readlane(scan, 63);     // SGPR
        int excl  = (int)cnt + scan - myc;
        int w = excl;
#pragma unroll
        for (int n = 0; n < NP; ++n) {
            if ((rel >> n) & 1u) { if (w < CAP) lst[w] = make_uint2(w0[n], w1[n]); ++w; }
        }
        cnt += (unsigned)total;
    }
    if (cnt > CAP) cnt = CAP;
    unsigned cntp = (cnt + 7u) & ~7u;
    if (cntp > CAP) cntp = CAP;
    if (lane < (int)(cntp - cnt)) lst[cnt + lane] = make_uint2(0u, 0u); // pad: zero masks
    int cntN = (int)cntp;

    // ---- apply: batch-of-8, straight-line masked ops, rcp off-chain ----
    int r8 = lane >> 3, c8 = lane & 7;
    int r  = ty0 + r8;
    int cc = tx0 + c8;
    float im = img[bc * (HH * WW) + r * WW + cc];
    float c  = 1.0f;
    const float* ds = pd + (size_t)bc * ((size_t)NEV * 49);
    int vOff2 = (r8 * 7 + c8) * 4 + 192;   // per-lane byte offset + s8q bias

    for (int i = 0; i < cntN; i += 8) {
        unsigned u0[8], u1[8];
        float    dv[8];
#pragma unroll
        for (int j = 0; j < 4; ++j) {      // 4x ds_read_b128 (2 entries each)
            uint4 e2 = *reinterpret_cast<const uint4*>(&lst[i + 2 * j]);
            u0[2 * j]     = (unsigned)__builtin_amdgcn_readfirstlane((int)e2.x);
            u1[2 * j]     = (unsigned)__builtin_amdgcn_readfirstlane((int)e2.y);
            u0[2 * j + 1] = (unsigned)__builtin_amdgcn_readfirstlane((int)e2.z);
            u1[2 * j + 1] = (unsigned)__builtin_amdgcn_readfirstlane((int)e2.w);
        }
        unsigned long long hm[8], cm[8];
#pragma unroll
        for (int j = 0; j < 8; ++j) {      // 16x s_load_dwordx2 from 2KB K$-hot table
            hm[j] = mt[u1[j] & 255u];
            cm[j] = mt[(u1[j] >> 8) & 255u];
        }
#pragma unroll
        for (int j = 0; j < 8; ++j) {      // 8x global_load v,off,s[base]
            int t_ = (int)(u0[j] & 16383u);
            const char* dsb = (const char*)(ds + (size_t)t_ * 49);
            int boc = vOff2 - (int)((u1[j] >> 16) & 511u);  // unclamped (safe)
            dv[j] = *(const float*)(dsb + boc);
        }
        // counter chain + rcp: independent of im, precomputed (bit-identical)
        float inc[8], cv[8], rv[8];
#pragma unroll
        for (int j = 0; j < 8; ++j)
            asm("v_cndmask_b32 %0, 0, 1.0, %1" : "=v"(inc[j]) : "s"(cm[j]));
        cv[0] = c;
#pragma unroll
        for (int j = 1; j < 8; ++j) cv[j] = cv[j - 1] + inc[j - 1];
        c = cv[7] + inc[7];
#pragma unroll
        for (int j = 0; j < 8; ++j) rv[j] = __builtin_amdgcn_rcpf(cv[j] + 1.0f);
        // im fold: fmaf -> mul -> cndmask per entry (12cy links)
#pragma unroll
        for (int j = 0; j < 8; ++j) {
            float nim = fmaf(im, cv[j], dv[j]) * rv[j];
            asm("v_cndmask_b32 %0, %0, %1, %2" : "+v"(im) : "v"(nim), "s"(hm[j]));
        }
    }
    out[bc * (HH * WW) + r * WW + cc] = im;
}

extern "C" void kernel_launch(void* const* d_in, const int* in_sizes, int n_in,
                              void* d_out, int out_size, void* d_ws, size_t ws_size,
                              hipStream_t stream) {
    const float* img = (const float*)d_in[0];
    const float* Wp  = (const float*)d_in[1];
    const float* bp  = (const float*)d_in[2];
    const float* pe  = (const float*)d_in[3];
    const float* Wb  = (const float*)d_in[4];
    const float* bb  = (const float*)d_in[5];
    float* out = (float*)d_out;

    float* wsf = (float*)d_ws;
    float*              M  = wsf;                               // 2401 floats (pad 2404)
    float*              K  = wsf + 2404;                        // 490 floats (pad 492)
    unsigned long long* MT = (unsigned long long*)(wsf + 2896); // 256 u64 = 512 floats
    unsigned*           xy = (unsigned*)(wsf + 3408);           // 414720 u32
    float*              pd = wsf + 3408 + NTASK;                // 20,321,280 floats

    k_mk<<<13, 256, 0, stream>>>(Wp, bp, pe, Wb, bb, M, K, MT);
    k_sim<<<BCN * PPOS / 4, 256, 0, stream>>>(img, M, K, xy, pd);
    k_apply<<<BCN * NTILE / 2, 128, 0, stream>>>(img, xy, pd, MT, out);
}

// Round 9
// 285.026 us; speedup vs baseline: 1.0509x; 1.0083x over previous
//
#include <hip/hip_runtime.h>

#define PS 7
#define NP 10
#define WIN 20
#define STR 4
#define LL 14          // WIN - PS + 1
#define HALF 7
#define HH 160
#define WW 160
#define BCN 32         // B*C
#define NX 36          // positions per axis
#define PPOS 1296      // NX*NX
#define EMBD 128
#define NTASK (BCN * PPOS * NP)   // 414720
#define NEV (PPOS * NP)           // 12960 events per plane
#define CAP 512                   // per-tile event list capacity (8x8 tiles)
#define NTILE 400                 // 20x20 tiles of 8x8 per plane

// ---------------- phase 0: M = Wp@Wb ([j][d]), K[n] = (bp+pos_emb[n])@Wb + bb
// M[j*49+d]: k_sim reads column d coalesced (Mc[j] = M[j*49+ld]).
// Also builds the 16x16 u64 lane-mask table MT (see k_apply).
__global__ __launch_bounds__(256) void k_mk(const float* __restrict__ Wp,
                                            const float* __restrict__ bp,
                                            const float* __restrict__ pe,
                                            const float* __restrict__ Wb,
                                            const float* __restrict__ bb,
                                            float* __restrict__ M,
                                            float* __restrict__ K,
                                            unsigned long long* __restrict__ MT) {
    int t = blockIdx.x * 256 + threadIdx.x;
    if (t < 49 * 49) {
        int k = t / 49, d = t % 49;
        float acc = 0.f;
        for (int e = 0; e < EMBD; ++e) acc += Wp[k * EMBD + e] * Wb[e * 49 + d];
        M[t] = acc;                        // M[j][d]
    } else if (t < 49 * 49 + NP * 49) {
        int u = t - 49 * 49;
        int n = u / 49, d = u % 49;
        float acc = bb[d];
        for (int e = 0; e < EMBD; ++e) acc += (bp[e] + pe[n * EMBD + e]) * Wb[e * 49 + d];
        K[u] = acc;
    } else if (t < 49 * 49 + NP * 49 + 256) {
        int u = t - (49 * 49 + NP * 49);
        int ey = (u >> 4) - 7, ex = (u & 15) - 7;
        int r0 = ey > 0 ? ey : 0, r1 = ey + 6 < 7 ? ey + 6 : 7;
        int c0 = ex > 0 ? ex : 0, c1 = ex + 6 < 7 ? ex + 6 : 7;
        unsigned long long m = 0ull;
        if (r0 <= r1 && c0 <= c1) {
            unsigned colp = ((1u << (c1 - c0 + 1)) - 1u) << c0;
            for (int rr = r0; rr <= r1; ++rr)
                m |= (unsigned long long)colp << (8 * rr);
        }
        MT[u] = m;
    }
}

// DPP wave64 INCLUSIVE add-scan: pure VALU (no ds_permute / lgkmcnt).
__device__ __forceinline__ int dpp_scan_add(int x) {
    int t;
    t = __builtin_amdgcn_update_dpp(0, x, 0x111, 0xf, 0xf, true);  x += t;
    t = __builtin_amdgcn_update_dpp(0, x, 0x112, 0xf, 0xf, true);  x += t;
    t = __builtin_amdgcn_update_dpp(0, x, 0x114, 0xf, 0xf, true);  x += t;
    t = __builtin_amdgcn_update_dpp(0, x, 0x118, 0xf, 0xf, true);  x += t;
    t = __builtin_amdgcn_update_dpp(0, x, 0x142, 0xa, 0xf, false); x += t;
    t = __builtin_amdgcn_update_dpp(0, x, 0x143, 0xc, 0xf, false); x += t;
    return x;
}

// ---------------- phase 1: sim + top-10 + FUSED den (round-2 proven body) ----
// This is the EXACT body that measured 126.28-126.64us (round-2 bench) — the
// empirical floor across all k_sim variants tried (r3 DPP+pipeline 125.8-127.8,
// r4 split ~167 combined, r8 LDS-tap 133.9). 4 independent waves per block
// (no LDS, no barriers). CRITICAL (round-18 lesson): wv must go through
// readfirstlane so pos/x/y/plane stay in SGPRs.
__global__ __launch_bounds__(256) void k_sim(const float* __restrict__ img,
                                             const float* __restrict__ Mg,
                                             const float* __restrict__ Kg,
                                             unsigned* __restrict__ xy,
                                             float* __restrict__ pd) {
    int tid  = threadIdx.x;
    int wv   = __builtin_amdgcn_readfirstlane(tid >> 6);   // SGPR wave id
    int lane = tid & 63;
    int gt   = blockIdx.x * 4 + wv;    // SALU
    int pos  = gt % PPOS;
    int bc   = gt / PPOS;
    int ix = pos / NX, iy = pos % NX;
    int x = ix * STR, y = iy * STR;
    int xb0 = max(x - HALF, 0), yb0 = max(y - HALF, 0);
    int jmax = x + 6 - xb0;   // valid j <= jmax
    int imax = y + 6 - yb0;   // <= 13 always
    const float* plane = img + bc * (HH * WW);   // SGPR base

    // ref patch 7x7, wave-uniform -> s_loads
    float rf[49];
#pragma unroll
    for (int a = 0; a < PS; ++a)
#pragma unroll
        for (int b = 0; b < PS; ++b)
            rf[a * 7 + b] = plane[(y + a) * WW + (x + b)];

    int B = lane;                      // quad block id, valid < 56
    bool bval = B < 56;
    int gr = B / 14, c = B % 14;       // row-group, col
    int r0 = gr * 4;
    float acc[4] = {0.f, 0.f, 0.f, 0.f};
    const float* wb = plane + yb0 * WW + xb0 + c;
#pragma unroll
    for (int a = 0; a < 10; ++a) {
        int ra = min(r0 + a, 19);      // clamp keeps loads in-window
        const float* rp = wb + ra * WW;
#pragma unroll
        for (int b = 0; b < 7; ++b) {
            float tap = rp[b];
#pragma unroll
            for (int k = 0; k < 4; ++k) {
                int ai = a - k;
                if (ai >= 0 && ai < 7) acc[k] += tap * rf[ai * 7 + b];
            }
        }
    }
    float v[4]; int vidx[4];
#pragma unroll
    for (int k = 0; k < 4; ++k) {
        int rr = r0 + k;
        bool ok = bval && (rr <= imax) && (c <= jmax);  // imax<=13 masks rows 14/15
        v[k] = ok ? acc[k] : -INFINITY;
        vidx[k] = rr * 14 + c;         // monotone in lane per slot
    }

    // M column d cached per lane (rf[] live range ends above -> regs reused)
    int ld = min(lane, 48);
    float Mc[49];
#pragma unroll
    for (int j = 0; j < 49; ++j) Mc[j] = Mg[j * 49 + ld];  // coalesced, L1-hot

    bool act = lane < 49;
    int tbase = (bc * PPOS + pos) * NP;

    for (int n = 0; n < NP; ++n) {
        float bv = fmaxf(fmaxf(v[0], v[1]), fmaxf(v[2], v[3]));
#pragma unroll
        for (int off = 32; off >= 1; off >>= 1)
            bv = fmaxf(bv, __shfl_xor(bv, off));
        unsigned long long ms[4];
        ms[0] = __ballot(v[0] == bv);
        ms[1] = __ballot(v[1] == bv);
        ms[2] = __ballot(v[2] == bv);
        ms[3] = __ballot(v[3] == bv);
        int best = 1 << 30, slotw = 0, lanew = 0;
#pragma unroll
        for (int s = 0; s < 4; ++s) {
            if (ms[s]) {
                int l  = __ffsll(ms[s]) - 1;                       // SGPR
                int id = __builtin_amdgcn_readlane(vidx[s], l);    // SGPR
                if (id < best) { best = id; slotw = s; lanew = l; }
            }
        }
        int bi = best;                       // SGPR raster idx (unique)
#pragma unroll
        for (int s = 0; s < 4; ++s)
            if (s == slotw && lane == lanew) v[s] = -INFINITY;

        int oy = bi / 14, ox = bi % 14;      // SALU
        int x_i = oy + xb0;        // source bug kept: col start = row off + xb0
        int y_i = ox + yb0;        // row start = col off + yb0
        int t = tbase + n;
        if (lane == 0) xy[t] = (unsigned)x_i | ((unsigned)y_i << 8);
        const float* src = plane + (yb0 + oy) * WW + (xb0 + ox);   // SGPR base
        // den[lane] = K[n][lane] + sum_j patch_j * Mc[j];
        // patch_j = src[(j%7)*WW + j/7]  (transposed patch, uniform -> s_load)
        // 4 independent FMA chains, summed pairwise (round-2 order).
        float d0 = Kg[n * 49 + ld], d1 = 0.f, d2 = 0.f, d3 = 0.f;
#pragma unroll
        for (int j = 0; j < 48; j += 4) {
            d0 = fmaf(src[((j + 0) % 7) * WW + ((j + 0) / 7)], Mc[j + 0], d0);
            d1 = fmaf(src[((j + 1) % 7) * WW + ((j + 1) / 7)], Mc[j + 1], d1);
            d2 = fmaf(src[((j + 2) % 7) * WW + ((j + 2) / 7)], Mc[j + 2], d2);
            d3 = fmaf(src[((j + 3) % 7) * WW + ((j + 3) / 7)], Mc[j + 3], d3);
        }
        d0 = fmaf(src[(48 % 7) * WW + (48 / 7)], Mc[48], d0);
        float den = (d0 + d1) + (d2 + d3);
        if (act) pd[(size_t)t * 49 + lane] = den;
    }
}

// ---------------- phase 3: build (LDS uint2 list) + replay -------------------
// EXACT round-7 body (measured 102.8-105.3us): straight-line masked ops, rcp
// off the im critical chain, unclamped boc, XCD-bijective swizzle, DPP scan.
__global__ __launch_bounds__(128) void k_apply(const float* __restrict__ img,
                                               const unsigned* __restrict__ xy,
                                               const float* __restrict__ pd,
                                               const unsigned long long* __restrict__ mt,
                                               float* __restrict__ out) {
    __shared__ __align__(16) uint2 lsts[2][CAP];
    int tid  = threadIdx.x;
    int wv   = tid >> 6;
    int lane = tid & 63;
    int bs   = (blockIdx.x & 7) * 800 + (blockIdx.x >> 3);  // XCD-bijective
    int gt   = bs * 2 + wv;                  // global tile id
    int bc   = gt / NTILE;
    int tile = gt % NTILE;
    int tx0 = (tile % 20) * 8, ty0 = (tile / 20) * 8;
    int tx1 = tx0 + 7, ty1 = ty0 + 7;
    const unsigned* xs = xy + bc * NEV;
    uint2* lst = lsts[wv];

    // ---- build: interval-restricted scan ----
    int a0 = (tx0 <= 19) ? 0 : ((tx0 - 9) >> 2), a1 = min(35, (tx0 + 14) >> 2);
    int b0 = (ty0 <= 19) ? 0 : ((ty0 - 9) >> 2), b1 = min(35, (ty0 + 14) >> 2);
    if (a0 > b0) { int t0 = a0; a0 = b0; b0 = t0; int t1 = a1; a1 = b1; b1 = t1; }
    int lo0 = a0, lo1 = 0, len0, len1;
    if (b0 <= a1 + 1) { len0 = max(a1, b1) - lo0 + 1; len1 = 0; }
    else              { len0 = a1 - a0 + 1; lo1 = b0; len1 = b1 - b0 + 1; }
    int nU = len0 + len1;                    // <= 14
    unsigned m = 65536u / (unsigned)nU + 1u; // exact fastdiv (k < 4681, nU <= 14)
    int npos = nU * nU;

    unsigned cnt = 0;
    for (int base = 0; base < npos; base += 64) {
        int k = base + lane;
        bool valid = k < npos;
        unsigned kk = valid ? (unsigned)k : 0u;
        int ki = (int)((kk * m) >> 16);
        int kj = (int)kk - ki * nU;
        int ixp = (ki < len0) ? (lo0 + ki) : (lo1 + ki - len0);
        int iyp = (kj < len0) ? (lo0 + kj) : (lo1 + kj - len0);
        int pos = ixp * NX + iyp;
        const unsigned* ep = xs + pos * NP;

        unsigned ev[NP];
#pragma unroll
        for (int n = 0; n < NP; ++n) ev[n] = ep[n];

        unsigned rel = 0;
        unsigned w0[NP], w1[NP];
#pragma unroll
        for (int n = 0; n < NP; ++n) {
            unsigned u = ev[n];
            int x_i = (int)(u & 255u);
            int y_i = (int)((u >> 8) & 255u);
            int exH = x_i - tx0, eyH = y_i - ty0;   // shared subs (CSE with pack)
            int eyC = x_i - ty0, exC = y_i - tx0;
            bool ih = ((unsigned)(exH + 6) <= 13u) & ((unsigned)(eyH + 6) <= 13u);
            bool ch = ((unsigned)(eyC + 6) <= 13u) & ((unsigned)(exC + 6) <= 13u);
            bool any = valid && (ih || ch);
            rel |= any ? (1u << n) : 0u;
            unsigned hidx = ih ? (unsigned)(((eyH + 7) << 4) | (exH + 7)) : 0u;
            unsigned cidx = ch ? (unsigned)(((eyC + 7) << 4) | (exC + 7)) : 0u;
            unsigned s8q  = ih ? (unsigned)(((7 * eyH + exH) + 48) << 2) : 0u; // <=416, 9b
            w0[n] = (unsigned)(pos * NP + n);
            w1[n] = hidx | (cidx << 8) | (s8q << 16);
        }
        int myc  = __popc(rel);
        int scan = dpp_scan_add(myc);                        // VALU-only scan
        int total = __builtin_amdgcn_readlane(scan, 63);     // SGPR
        int excl  = (int)cnt + scan - myc;
        int w = excl;
#pragma unroll
        for (int n = 0; n < NP; ++n) {
            if ((rel >> n) & 1u) { if (w < CAP) lst[w] = make_uint2(w0[n], w1[n]); ++w; }
        }
        cnt += (unsigned)total;
    }
    if (cnt > CAP) cnt = CAP;
    unsigned cntp = (cnt + 7u) & ~7u;
    if (cntp > CAP) cntp = CAP;
    if (lane < (int)(cntp - cnt)) lst[cnt + lane] = make_uint2(0u, 0u); // pad: zero masks
    int cntN = (int)cntp;

    // ---- apply: batch-of-8, straight-line masked ops, rcp off-chain ----
    int r8 = lane >> 3, c8 = lane & 7;
    int r  = ty0 + r8;
    int cc = tx0 + c8;
    float im = img[bc * (HH * WW) + r * WW + cc];
    float c  = 1.0f;
    const float* ds = pd + (size_t)bc * ((size_t)NEV * 49);
    int vOff2 = (r8 * 7 + c8) * 4 + 192;   // per-lane byte offset + s8q bias

    for (int i = 0; i < cntN; i += 8) {
        unsigned u0[8], u1[8];
        float    dv[8];
#pragma unroll
        for (int j = 0; j < 4; ++j) {      // 4x ds_read_b128 (2 entries each)
            uint4 e2 = *reinterpret_cast<const uint4*>(&lst[i + 2 * j]);
            u0[2 * j]     = (unsigned)__builtin_amdgcn_readfirstlane((int)e2.x);
            u1[2 * j]     = (unsigned)__builtin_amdgcn_readfirstlane((int)e2.y);
            u0[2 * j + 1] = (unsigned)__builtin_amdgcn_readfirstlane((int)e2.z);
            u1[2 * j + 1] = (unsigned)__builtin_amdgcn_readfirstlane((int)e2.w);
        }
        unsigned long long hm[8], cm[8];
#pragma unroll
        for (int j = 0; j < 8; ++j) {      // 16x s_load_dwordx2 from 2KB K$-hot table
            hm[j] = mt[u1[j] & 255u];
            cm[j] = mt[(u1[j] >> 8) & 255u];
        }
#pragma unroll
        for (int j = 0; j < 8; ++j) {      // 8x global_load v,off,s[base]
            int t_ = (int)(u0[j] & 16383u);
            const char* dsb = (const char*)(ds + (size_t)t_ * 49);
            int boc = vOff2 - (int)((u1[j] >> 16) & 511u);  // unclamped (safe)
            dv[j] = *(const float*)(dsb + boc);
        }
        // counter chain + rcp: independent of im, precomputed (bit-identical)
        float inc[8], cv[8], rv[8];
#pragma unroll
        for (int j = 0; j < 8; ++j)
            asm("v_cndmask_b32 %0, 0, 1.0, %1" : "=v"(inc[j]) : "s"(cm[j]));
        cv[0] = c;
#pragma unroll
        for (int j = 1; j < 8; ++j) cv[j] = cv[j - 1] + inc[j - 1];
        c = cv[7] + inc[7];
#pragma unroll
        for (int j = 0; j < 8; ++j) rv[j] = __builtin_amdgcn_rcpf(cv[j] + 1.0f);
        // im fold: fmaf -> mul -> cndmask per entry (12cy links)
#pragma unroll
        for (int j = 0; j < 8; ++j) {
            float nim = fmaf(im, cv[j], dv[j]) * rv[j];
            asm("v_cndmask_b32 %0, %0, %1, %2" : "+v"(im) : "v"(nim), "s"(hm[j]));
        }
    }
    out[bc * (HH * WW) + r * WW + cc] = im;
}

extern "C" void kernel_launch(void* const* d_in, const int* in_sizes, int n_in,
                              void* d_out, int out_size, void* d_ws, size_t ws_size,
                              hipStream_t stream) {
    const float* img = (const float*)d_in[0];
    const float* Wp  = (const float*)d_in[1];
    const float* bp  = (const float*)d_in[2];
    const float* pe  = (const float*)d_in[3];
    const float* Wb  = (const float*)d_in[4];
    const float* bb  = (const float*)d_in[5];
    float* out = (float*)d_out;

    float* wsf = (float*)d_ws;
    float*              M  = wsf;                               // 2401 floats (pad 2404)
    float*              K  = wsf + 2404;                        // 490 floats (pad 492)
    unsigned long long* MT = (unsigned long long*)(wsf + 2896); // 256 u64 = 512 floats
    unsigned*           xy = (unsigned*)(wsf + 3408);           // 414720 u32
    float*              pd = wsf + 3408 + NTASK;                // 20,321,280 floats

    k_mk<<<13, 256, 0, stream>>>(Wp, bp, pe, Wb, bb, M, K, MT);
    k_sim<<<BCN * PPOS / 4, 256, 0, stream>>>(img, M, K, xy, pd);
    k_apply<<<BCN * NTILE / 2, 128, 0, stream>>>(img, xy, pd, MT, out);
}